// Round 1
// baseline (200.437 us; speedup 1.0000x reference)
//
#include <hip/hip_runtime.h>
#include <hip/hip_bf16.h>

#define CNUM 100
#define NS   8192
#define DIM  768
#define BF   1024
#define SP   12288   // padded sample stride: >= NS + CNUM*31 (=11292), mult of 128
#define PHI_SZ ((size_t)CNUM * BF * BF)
#define MU_SZ  ((size_t)CNUM * BF)

typedef float f32x4 __attribute__((ext_vector_type(4)));
typedef short s16x8 __attribute__((ext_vector_type(8)));
typedef unsigned short u16x8 __attribute__((ext_vector_type(8)));

static __device__ __forceinline__ unsigned short f2bf(float x) {
  union { float f; unsigned int u; } v; v.f = x;
  unsigned int lsb = (v.u >> 16) & 1;
  v.u += 0x7fffu + lsb;                 // round-to-nearest-even
  return (unsigned short)(v.u >> 16);
}

static __device__ __forceinline__ float bf2f(unsigned short u) {
  return __uint_as_float(((unsigned int)u) << 16);
}

// ---------------- small prep kernels ----------------

__global__ void k_hist(const int* __restrict__ lab, int* __restrict__ counts) {
  int n = blockIdx.x * 256 + threadIdx.x;
  if (n < NS) atomicAdd(&counts[lab[n]], 1);
}

__global__ void k_prefix(const int* __restrict__ counts, int* __restrict__ poff,
                         float* __restrict__ outCounts) {
  if (threadIdx.x == 0) {
    int acc = 0;
    for (int c = 0; c < CNUM; ++c) {
      poff[c] = acc;
      acc += (counts[c] + 31) & ~31;    // pad each class to mult of 32 (MFMA K)
    }
    poff[CNUM] = acc;
  }
  if (threadIdx.x < CNUM) outCounts[threadIdx.x] = (float)counts[threadIdx.x];
}

__global__ void k_scatter(const int* __restrict__ lab, const int* __restrict__ poff,
                          int* __restrict__ rank, int* __restrict__ sIdx) {
  int n = blockIdx.x * 256 + threadIdx.x;
  if (n < NS) {
    int c = lab[n];
    int r = atomicAdd(&rank[c], 1);
    sIdx[poff[c] + r] = n;
  }
}

__global__ void k_xbf(const float* __restrict__ X, unsigned short* __restrict__ Xbf) {
  size_t i = ((size_t)blockIdx.x * 256 + threadIdx.x) * 4;
  float4 v = *(const float4*)(X + i);
  *(ushort4*)(Xbf + i) = make_ushort4(f2bf(v.x), f2bf(v.y), f2bf(v.z), f2bf(v.w));
}

// W[k][f] fp32 -> WT[f][k] bf16 via LDS-tiled transpose
__global__ void k_wt(const float* __restrict__ W, unsigned short* __restrict__ WT) {
  __shared__ float tile[32][33];
  const int kb = blockIdx.x * 32;
  const int fb = blockIdx.y * 32;
  const int t = threadIdx.x;
  {
    const int cc = t & 31, r4 = t >> 5;
#pragma unroll
    for (int i = 0; i < 4; ++i) {
      int r = r4 * 4 + i;
      tile[r][cc] = W[(size_t)(kb + r) * BF + fb + cc];
    }
  }
  __syncthreads();
  {
    const int kc = t & 31, f4 = t >> 5;
#pragma unroll
    for (int i = 0; i < 4; ++i) {
      int fr = f4 * 4 + i;
      WT[(size_t)(fb + fr) * DIM + kb + kc] = f2bf(tile[kc][fr]);
    }
  }
}

// ---------------- GEMM1: featT[f][s] = relu( Xbf[sIdx[s]] @ W )[f], bf16 ----------------

__global__ __launch_bounds__(256) void k_gemm1(
    const unsigned short* __restrict__ Xbf,  // [NS][DIM] bf16
    const unsigned short* __restrict__ WT,   // [BF][DIM] bf16
    const int* __restrict__ sIdx,            // [SP], -1 = pad
    unsigned short* __restrict__ featT)      // [BF][SP] bf16
{
  __shared__ __align__(16) unsigned short As[128][40];
  __shared__ __align__(16) unsigned short Bs[128][40];

  const int t = threadIdx.x;
  const int f0 = blockIdx.x * 128;
  const int s0 = blockIdx.y * 128;
  const int lane = t & 63;
  const int wave = t >> 6;
  const int wr = wave >> 1, wc = wave & 1;
  const int srow = t >> 1, shalf = t & 1;
  const int n = sIdx[s0 + srow];

  f32x4 acc[4][4];
#pragma unroll
  for (int m = 0; m < 4; ++m)
#pragma unroll
    for (int q = 0; q < 4; ++q) acc[m][q] = (f32x4)0.0f;

  const unsigned short* aSrc = (n >= 0) ? (Xbf + (size_t)n * DIM + shalf * 16) : 0;
  const unsigned short* bSrc = WT + (size_t)(f0 + srow) * DIM + shalf * 16;

  for (int kt = 0; kt < DIM / 32; ++kt) {
    u16x8 av0, av1, bv0, bv1;
    if (aSrc) {
      av0 = *(const u16x8*)(aSrc + kt * 32);
      av1 = *(const u16x8*)(aSrc + kt * 32 + 8);
    } else {
      av0 = (u16x8)0; av1 = (u16x8)0;
    }
    bv0 = *(const u16x8*)(bSrc + kt * 32);
    bv1 = *(const u16x8*)(bSrc + kt * 32 + 8);

    __syncthreads();
    *(u16x8*)&As[srow][shalf * 16]     = av0;
    *(u16x8*)&As[srow][shalf * 16 + 8] = av1;
    *(u16x8*)&Bs[srow][shalf * 16]     = bv0;
    *(u16x8*)&Bs[srow][shalf * 16 + 8] = bv1;
    __syncthreads();

    s16x8 a[4], b[4];
#pragma unroll
    for (int m = 0; m < 4; ++m)
      a[m] = *(const s16x8*)&As[wr * 64 + m * 16 + (lane & 15)][(lane >> 4) * 8];
#pragma unroll
    for (int q = 0; q < 4; ++q)
      b[q] = *(const s16x8*)&Bs[wc * 64 + q * 16 + (lane & 15)][(lane >> 4) * 8];
#pragma unroll
    for (int m = 0; m < 4; ++m)
#pragma unroll
      for (int q = 0; q < 4; ++q)
        acc[m][q] = __builtin_amdgcn_mfma_f32_16x16x32_bf16(a[m], b[q], acc[m][q], 0, 0, 0);
  }

  // epilogue: relu + bf16, transposed store into featT[f][s] (8B per lane per frag)
  const int rbase = s0 + wr * 64 + ((lane >> 4) << 2);
  const int cbase = f0 + wc * 64 + (lane & 15);
#pragma unroll
  for (int m = 0; m < 4; ++m) {
#pragma unroll
    for (int q = 0; q < 4; ++q) {
      f32x4 v = acc[m][q];
      unsigned short p0 = f2bf(fmaxf(v[0], 0.f));
      unsigned short p1 = f2bf(fmaxf(v[1], 0.f));
      unsigned short p2 = f2bf(fmaxf(v[2], 0.f));
      unsigned short p3 = f2bf(fmaxf(v[3], 0.f));
      const int s = rbase + m * 16;
      const int f = cbase + q * 16;
      *(ushort4*)(featT + (size_t)f * SP + s) = make_ushort4(p0, p1, p2, p3);
    }
  }
}

// ---------------- phi: per-class SYRK, phi[c][i][j] = sum_k featT[i][k]*featT[j][k] ----------------

__global__ __launch_bounds__(256) void k_phi(
    const unsigned short* __restrict__ featT,
    const int* __restrict__ poff,
    float* __restrict__ out)
{
  __shared__ __align__(16) unsigned short As[128][40];
  __shared__ __align__(16) unsigned short Bs[128][40];

  const int t = threadIdx.x;
  const int c = blockIdx.z;
  const int i0 = blockIdx.y * 128;
  const int j0 = blockIdx.x * 128;
  const int lane = t & 63;
  const int wave = t >> 6;
  const int wr = wave >> 1, wc = wave & 1;
  const int row = t >> 1, half = t & 1;

  const int kb0 = poff[c];
  const int ksteps = (poff[c + 1] - kb0) >> 5;

  f32x4 acc[4][4];
#pragma unroll
  for (int m = 0; m < 4; ++m)
#pragma unroll
    for (int q = 0; q < 4; ++q) acc[m][q] = (f32x4)0.0f;

  const unsigned short* aSrc = featT + (size_t)(i0 + row) * SP + kb0 + half * 16;
  const unsigned short* bSrc = featT + (size_t)(j0 + row) * SP + kb0 + half * 16;

  for (int kt = 0; kt < ksteps; ++kt) {
    u16x8 av0 = *(const u16x8*)(aSrc + kt * 32);
    u16x8 av1 = *(const u16x8*)(aSrc + kt * 32 + 8);
    u16x8 bv0 = *(const u16x8*)(bSrc + kt * 32);
    u16x8 bv1 = *(const u16x8*)(bSrc + kt * 32 + 8);

    __syncthreads();
    *(u16x8*)&As[row][half * 16]     = av0;
    *(u16x8*)&As[row][half * 16 + 8] = av1;
    *(u16x8*)&Bs[row][half * 16]     = bv0;
    *(u16x8*)&Bs[row][half * 16 + 8] = bv1;
    __syncthreads();

    s16x8 a[4], b[4];
#pragma unroll
    for (int m = 0; m < 4; ++m)
      a[m] = *(const s16x8*)&As[wr * 64 + m * 16 + (lane & 15)][(lane >> 4) * 8];
#pragma unroll
    for (int q = 0; q < 4; ++q)
      b[q] = *(const s16x8*)&Bs[wc * 64 + q * 16 + (lane & 15)][(lane >> 4) * 8];
#pragma unroll
    for (int m = 0; m < 4; ++m)
#pragma unroll
      for (int q = 0; q < 4; ++q)
        acc[m][q] = __builtin_amdgcn_mfma_f32_16x16x32_bf16(a[m], b[q], acc[m][q], 0, 0, 0);
  }

  float* phiC = out + (size_t)c * (BF * BF);
  const int rbase = i0 + wr * 64 + ((lane >> 4) << 2);
  const int cbase = j0 + wc * 64 + (lane & 15);
#pragma unroll
  for (int m = 0; m < 4; ++m) {
#pragma unroll
    for (int q = 0; q < 4; ++q) {
      f32x4 v = acc[m][q];
#pragma unroll
      for (int r = 0; r < 4; ++r)
        phiC[(size_t)(rbase + m * 16 + r) * BF + (cbase + q * 16)] = v[r];
    }
  }
}

// ---------------- mu: per-class column-range sums of featT ----------------

__global__ __launch_bounds__(256) void k_mu(
    const unsigned short* __restrict__ featT,
    const int* __restrict__ poff,
    float* __restrict__ mu)
{
  const int c = blockIdx.y;
  const int lane = threadIdx.x & 63;
  const int wave = threadIdx.x >> 6;
  const int k0 = poff[c], k1 = poff[c + 1];
#pragma unroll 1
  for (int i = 0; i < 16; ++i) {
    const int f = blockIdx.x * 64 + wave * 16 + i;
    float s = 0.f;
    for (int b = k0 + lane; b < k1; b += 64)
      s += bf2f(featT[(size_t)f * SP + b]);
#pragma unroll
    for (int off = 32; off > 0; off >>= 1) s += __shfl_down(s, off, 64);
    if (lane == 0) mu[(size_t)c * BF + f] = s;
  }
}

// ---------------- launch ----------------

extern "C" void kernel_launch(void* const* d_in, const int* in_sizes, int n_in,
                              void* d_out, int out_size, void* d_ws, size_t ws_size,
                              hipStream_t stream) {
  const float* X = (const float*)d_in[0];
  const float* W = (const float*)d_in[1];
  const int* lab = (const int*)d_in[2];
  float* out = (float*)d_out;
  char* ws = (char*)d_ws;

  int* counts = (int*)(ws + 0);
  int* poff   = (int*)(ws + 512);
  int* rank   = (int*)(ws + 1024);
  int* sIdx   = (int*)(ws + 2048);                         // SP ints
  unsigned short* featT = (unsigned short*)(ws + 65536);   // BF*SP bf16
  unsigned short* Xbf = (unsigned short*)(ws + 65536 + (size_t)BF * SP * 2);
  unsigned short* WT  = (unsigned short*)(ws + 65536 + (size_t)BF * SP * 2 + (size_t)NS * DIM * 2);

  hipMemsetAsync(ws, 0, 2048, stream);                     // counts, poff, rank
  hipMemsetAsync(sIdx, 0xFF, SP * sizeof(int), stream);    // sIdx = -1

  k_hist<<<NS / 256, 256, 0, stream>>>(lab, counts);
  k_prefix<<<1, 128, 0, stream>>>(counts, poff, out + PHI_SZ + MU_SZ);
  k_scatter<<<NS / 256, 256, 0, stream>>>(lab, poff, rank, sIdx);
  k_xbf<<<NS * DIM / 4 / 256, 256, 0, stream>>>(X, Xbf);
  k_wt<<<dim3(DIM / 32, BF / 32), 256, 0, stream>>>(W, WT);
  k_gemm1<<<dim3(BF / 128, SP / 128), 256, 0, stream>>>(Xbf, WT, sIdx, featT);
  k_phi<<<dim3(BF / 128, BF / 128, CNUM), 256, 0, stream>>>(featT, poff, out);
  k_mu<<<dim3(16, CNUM), 256, 0, stream>>>(featT, poff, out + (size_t)PHI_SZ);
}

// Round 2
// 172.856 us; speedup vs baseline: 1.1596x; 1.1596x over previous
//
#include <hip/hip_runtime.h>
#include <hip/hip_bf16.h>

#define CNUM 100
#define NS   8192
#define DIM  768
#define BF   1024
#define SP   12288   // padded sample stride: >= NS + CNUM*31 (=11292), mult of 128
#define PHI_SZ ((size_t)CNUM * BF * BF)
#define MU_SZ  ((size_t)CNUM * BF)

typedef float f32x4 __attribute__((ext_vector_type(4)));
typedef short s16x8 __attribute__((ext_vector_type(8)));

// async global->LDS, 16B per lane; dest must be wave-uniform base + lane*16 (linear LDS)
#define GL2LDS(gp, lp) __builtin_amdgcn_global_load_lds( \
    (const __attribute__((address_space(1))) void*)(gp), \
    (__attribute__((address_space(3))) void*)(lp), 16, 0, 0)

static __device__ __forceinline__ unsigned short f2bf(float x) {
  union { float f; unsigned int u; } v; v.f = x;
  unsigned int lsb = (v.u >> 16) & 1;
  v.u += 0x7fffu + lsb;                 // round-to-nearest-even
  return (unsigned short)(v.u >> 16);
}

static __device__ __forceinline__ float bf2f(unsigned short u) {
  return __uint_as_float(((unsigned int)u) << 16);
}

// ---------------- prep: hist + prefix + scatter + pad init, one block ----------------

__global__ __launch_bounds__(1024) void k_prep(
    const int* __restrict__ lab, int* __restrict__ sIdx, int* __restrict__ poff,
    float* __restrict__ outCounts, unsigned short* __restrict__ zeroPad)
{
  __shared__ int cnt[CNUM];
  __shared__ int off[CNUM + 1];
  __shared__ int rk[CNUM];
  const int t = threadIdx.x;
  if (t < CNUM) { cnt[t] = 0; rk[t] = 0; }
  __syncthreads();
  for (int n = t; n < NS; n += 1024) atomicAdd(&cnt[lab[n]], 1);
  for (int i = t; i < SP; i += 1024) sIdx[i] = -1;
  for (int i = t; i < DIM; i += 1024) zeroPad[i] = 0;
  __syncthreads();
  if (t == 0) {
    int a = 0;
    for (int c = 0; c < CNUM; ++c) { off[c] = a; a += (cnt[c] + 31) & ~31; }
    off[CNUM] = a;
  }
  __syncthreads();
  if (t < CNUM) outCounts[t] = (float)cnt[t];
  if (t <= CNUM) poff[t] = off[t];
  for (int n = t; n < NS; n += 1024) {
    int c = lab[n];
    int r = atomicAdd(&rk[c], 1);
    sIdx[off[c] + r] = n;
  }
}

// ---------------- cvt: X fp32 -> bf16, and W[k][f] -> WT[f][k] bf16 (fused) ----------------

__global__ __launch_bounds__(256) void k_cvt(
    const float* __restrict__ X, unsigned short* __restrict__ Xbf,
    const float* __restrict__ W, unsigned short* __restrict__ WT)
{
  __shared__ float tile[32][33];
  const int b = blockIdx.x;
  const int t = threadIdx.x;
  if (b < NS * DIM / 4 / 256) {
    size_t i = ((size_t)b * 256 + t) * 4;
    float4 v = *(const float4*)(X + i);
    *(ushort4*)(Xbf + i) = make_ushort4(f2bf(v.x), f2bf(v.y), f2bf(v.z), f2bf(v.w));
  } else {
    const int bb = b - NS * DIM / 4 / 256;
    const int kb = (bb % (DIM / 32)) * 32;
    const int fb = (bb / (DIM / 32)) * 32;
    {
      const int cc = t & 31, r4 = t >> 5;
#pragma unroll
      for (int i = 0; i < 4; ++i) {
        int r = r4 * 4 + i;
        tile[r][cc] = W[(size_t)(kb + r) * BF + fb + cc];
      }
    }
    __syncthreads();
    {
      const int kc = t & 31, f4 = t >> 5;
#pragma unroll
      for (int i = 0; i < 4; ++i) {
        int fr = f4 * 4 + i;
        WT[(size_t)(fb + fr) * DIM + kb + kc] = f2bf(tile[kc][fr]);
      }
    }
  }
}

// ---------------- GEMM1: featT[f][s] = relu( Xbf[sIdx[s]] @ W )[f], bf16 ----------------
// gload_lds staging: linear LDS [128][32], source pre-swizzled with q ^= (row>>1)&3,
// reads apply the same XOR -> 2-way bank access (free).

__global__ __launch_bounds__(256) void k_gemm1(
    const unsigned short* __restrict__ Xbf,  // [NS][DIM] bf16
    const unsigned short* __restrict__ WT,   // [BF][DIM] bf16
    const int* __restrict__ sIdx,            // [SP], -1 = pad
    const unsigned short* __restrict__ zeroPad,
    unsigned short* __restrict__ featT)      // [BF][SP] bf16
{
  __shared__ __align__(16) unsigned short As[128][32];
  __shared__ __align__(16) unsigned short Bs[128][32];

  const int t = threadIdx.x;
  const int f0 = blockIdx.x * 128;
  const int s0 = blockIdx.y * 128;
  const int lane = t & 63;
  const int wave = t >> 6;
  const int wr = wave >> 1, wc = wave & 1;

  // staging map: pass p in {0,1}: row r = p*64 + (t>>2), LDS 16B slot q' = t&3,
  // global quarter q = q' ^ ((r>>1)&3)
  const int rr = t >> 2, qp = t & 3;
  const int rA0 = rr, rA1 = 64 + rr;
  const int qg0 = qp ^ ((rA0 >> 1) & 3);
  const int qg1 = qp ^ ((rA1 >> 1) & 3);
  const int n0 = sIdx[s0 + rA0];
  const int n1 = sIdx[s0 + rA1];
  const unsigned short* aSrc0 = (n0 >= 0 ? Xbf + (size_t)n0 * DIM : zeroPad) + qg0 * 8;
  const unsigned short* aSrc1 = (n1 >= 0 ? Xbf + (size_t)n1 * DIM : zeroPad) + qg1 * 8;
  const unsigned short* bSrc0 = WT + (size_t)(f0 + rA0) * DIM + qg0 * 8;
  const unsigned short* bSrc1 = WT + (size_t)(f0 + rA1) * DIM + qg1 * 8;
  unsigned short* aDst = &As[0][0] + t * 8;   // t*16 bytes, wave-linear
  unsigned short* bDst = &Bs[0][0] + t * 8;

  f32x4 acc[4][4];
#pragma unroll
  for (int m = 0; m < 4; ++m)
#pragma unroll
    for (int q = 0; q < 4; ++q) acc[m][q] = (f32x4)0.0f;

  for (int kt = 0; kt < DIM / 32; ++kt) {
    __syncthreads();
    GL2LDS(aSrc0, aDst);
    GL2LDS(aSrc1, aDst + 2048);
    GL2LDS(bSrc0, bDst);
    GL2LDS(bSrc1, bDst + 2048);
    aSrc0 += 32; aSrc1 += 32; bSrc0 += 32; bSrc1 += 32;
    __syncthreads();

    s16x8 a[4], b[4];
#pragma unroll
    for (int m = 0; m < 4; ++m) {
      const int row = wr * 64 + m * 16 + (lane & 15);
      const int sq = (lane >> 4) ^ ((row >> 1) & 3);
      a[m] = *(const s16x8*)((const char*)As + row * 64 + sq * 16);
    }
#pragma unroll
    for (int q = 0; q < 4; ++q) {
      const int row = wc * 64 + q * 16 + (lane & 15);
      const int sq = (lane >> 4) ^ ((row >> 1) & 3);
      b[q] = *(const s16x8*)((const char*)Bs + row * 64 + sq * 16);
    }
#pragma unroll
    for (int m = 0; m < 4; ++m)
#pragma unroll
      for (int q = 0; q < 4; ++q)
        acc[m][q] = __builtin_amdgcn_mfma_f32_16x16x32_bf16(a[m], b[q], acc[m][q], 0, 0, 0);
  }

  // epilogue: relu + bf16, transposed store into featT[f][s]
  const int rbase = s0 + wr * 64 + ((lane >> 4) << 2);
  const int cbase = f0 + wc * 64 + (lane & 15);
#pragma unroll
  for (int m = 0; m < 4; ++m) {
#pragma unroll
    for (int q = 0; q < 4; ++q) {
      f32x4 v = acc[m][q];
      unsigned short p0 = f2bf(fmaxf(v[0], 0.f));
      unsigned short p1 = f2bf(fmaxf(v[1], 0.f));
      unsigned short p2 = f2bf(fmaxf(v[2], 0.f));
      unsigned short p3 = f2bf(fmaxf(v[3], 0.f));
      const int s = rbase + m * 16;
      const int f = cbase + q * 16;
      *(ushort4*)(featT + (size_t)f * SP + s) = make_ushort4(p0, p1, p2, p3);
    }
  }
}

// ---------------- phi: per-class SYRK via MFMA, gload_lds staging ----------------

__global__ __launch_bounds__(256) void k_phi(
    const unsigned short* __restrict__ featT,
    const int* __restrict__ poff,
    float* __restrict__ out)
{
  __shared__ __align__(16) unsigned short As[128][32];
  __shared__ __align__(16) unsigned short Bs[128][32];

  const int t = threadIdx.x;
  const int c = blockIdx.z;
  const int i0 = blockIdx.y * 128;
  const int j0 = blockIdx.x * 128;
  const int lane = t & 63;
  const int wave = t >> 6;
  const int wr = wave >> 1, wc = wave & 1;

  const int kb0 = poff[c];
  const int ksteps = (poff[c + 1] - kb0) >> 5;

  const int rr = t >> 2, qp = t & 3;
  const int rA0 = rr, rA1 = 64 + rr;
  const int qg0 = qp ^ ((rA0 >> 1) & 3);
  const int qg1 = qp ^ ((rA1 >> 1) & 3);
  const unsigned short* aSrc0 = featT + (size_t)(i0 + rA0) * SP + kb0 + qg0 * 8;
  const unsigned short* aSrc1 = featT + (size_t)(i0 + rA1) * SP + kb0 + qg1 * 8;
  const unsigned short* bSrc0 = featT + (size_t)(j0 + rA0) * SP + kb0 + qg0 * 8;
  const unsigned short* bSrc1 = featT + (size_t)(j0 + rA1) * SP + kb0 + qg1 * 8;
  unsigned short* aDst = &As[0][0] + t * 8;
  unsigned short* bDst = &Bs[0][0] + t * 8;

  f32x4 acc[4][4];
#pragma unroll
  for (int m = 0; m < 4; ++m)
#pragma unroll
    for (int q = 0; q < 4; ++q) acc[m][q] = (f32x4)0.0f;

  for (int kt = 0; kt < ksteps; ++kt) {
    __syncthreads();
    GL2LDS(aSrc0, aDst);
    GL2LDS(aSrc1, aDst + 2048);
    GL2LDS(bSrc0, bDst);
    GL2LDS(bSrc1, bDst + 2048);
    aSrc0 += 32; aSrc1 += 32; bSrc0 += 32; bSrc1 += 32;
    __syncthreads();

    s16x8 a[4], b[4];
#pragma unroll
    for (int m = 0; m < 4; ++m) {
      const int row = wr * 64 + m * 16 + (lane & 15);
      const int sq = (lane >> 4) ^ ((row >> 1) & 3);
      a[m] = *(const s16x8*)((const char*)As + row * 64 + sq * 16);
    }
#pragma unroll
    for (int q = 0; q < 4; ++q) {
      const int row = wc * 64 + q * 16 + (lane & 15);
      const int sq = (lane >> 4) ^ ((row >> 1) & 3);
      b[q] = *(const s16x8*)((const char*)Bs + row * 64 + sq * 16);
    }
#pragma unroll
    for (int m = 0; m < 4; ++m)
#pragma unroll
      for (int q = 0; q < 4; ++q)
        acc[m][q] = __builtin_amdgcn_mfma_f32_16x16x32_bf16(a[m], b[q], acc[m][q], 0, 0, 0);
  }

  float* phiC = out + (size_t)c * (BF * BF);
  const int rbase = i0 + wr * 64 + ((lane >> 4) << 2);
  const int cbase = j0 + wc * 64 + (lane & 15);
#pragma unroll
  for (int m = 0; m < 4; ++m) {
#pragma unroll
    for (int q = 0; q < 4; ++q) {
      f32x4 v = acc[m][q];
#pragma unroll
      for (int r = 0; r < 4; ++r)
        phiC[(size_t)(rbase + m * 16 + r) * BF + (cbase + q * 16)] = v[r];
    }
  }
}

// ---------------- mu: per-class column-range sums of featT ----------------

__global__ __launch_bounds__(256) void k_mu(
    const unsigned short* __restrict__ featT,
    const int* __restrict__ poff,
    float* __restrict__ mu)
{
  const int c = blockIdx.y;
  const int lane = threadIdx.x & 63;
  const int wave = threadIdx.x >> 6;
  const int k0 = poff[c], k1 = poff[c + 1];
#pragma unroll 1
  for (int i = 0; i < 16; ++i) {
    const int f = blockIdx.x * 64 + wave * 16 + i;
    float s = 0.f;
    for (int b = k0 + lane; b < k1; b += 64)
      s += bf2f(featT[(size_t)f * SP + b]);
#pragma unroll
    for (int off = 32; off > 0; off >>= 1) s += __shfl_down(s, off, 64);
    if (lane == 0) mu[(size_t)c * BF + f] = s;
  }
}

// ---------------- launch ----------------

extern "C" void kernel_launch(void* const* d_in, const int* in_sizes, int n_in,
                              void* d_out, int out_size, void* d_ws, size_t ws_size,
                              hipStream_t stream) {
  const float* X = (const float*)d_in[0];
  const float* W = (const float*)d_in[1];
  const int* lab = (const int*)d_in[2];
  float* out = (float*)d_out;
  char* ws = (char*)d_ws;

  int* poff = (int*)(ws);                                   // (CNUM+1) ints
  int* sIdx = (int*)(ws + 1024);                            // SP ints
  unsigned short* zeroPad = (unsigned short*)(ws + 1024 + SP * 4);  // DIM bf16 zeros
  unsigned short* featT = (unsigned short*)(ws + 65536);    // BF*SP bf16
  unsigned short* Xbf = (unsigned short*)(ws + 65536 + (size_t)BF * SP * 2);
  unsigned short* WT  = (unsigned short*)(ws + 65536 + (size_t)BF * SP * 2 + (size_t)NS * DIM * 2);

  k_prep<<<1, 1024, 0, stream>>>(lab, sIdx, poff, out + PHI_SZ + MU_SZ, zeroPad);
  k_cvt<<<NS * DIM / 4 / 256 + (DIM / 32) * (BF / 32), 256, 0, stream>>>(X, Xbf, W, WT);
  k_gemm1<<<dim3(BF / 128, SP / 128), 256, 0, stream>>>(Xbf, WT, sIdx, zeroPad, featT);
  k_phi<<<dim3(BF / 128, BF / 128, CNUM), 256, 0, stream>>>(featT, poff, out);
  k_mu<<<dim3(16, CNUM), 256, 0, stream>>>(featT, poff, out + (size_t)PHI_SZ);
}